// Round 8
// baseline (94.796 us; speedup 1.0000x reference)
//
#include <hip/hip_runtime.h>

// DeterministicEncoder: MLP encoder [M,2]->[M,64] + Laplace-kernel attention.
// exp(-|k-q|) factorizes: with context sorted by key, exclusive-prefix
// Lo[j] = sum_{i<j} e^{s_i} v_i and suffix Hi[j] = sum_{i>=j} e^{-s_i} v_i give
// out[n] = e^{-q} Lo[j_n] + e^{q} Hi[j_n], j_n = lower_bound(skey, q).
//
// Round 16: ledger: ~80.8us = two 256MiB harness poison fills (82-84% HBM
// peak, at roofline, not ours); our slice = ~8.7us (3 kernels + gaps).
// One cut this round, K1 rank loop only (rest round-15 verbatim, 89.5us):
//   rank counting via __ballot + popcount: the per-lane v_cmp_lt_u64+v_addc
//   pair (1024 VALU cyc/lane) becomes v_cmp only (512 cyc) with the
//   lane-sum done by s_bcnt1_b64 on the SCALAR pipe (runs concurrently,
//   wave-uniform cnt stays in SGPRs), and the 6-step x8-row shfl reduction
//   tree disappears entirely (ballot already reduced across lanes).
//   Identical count semantics -> bit-identical permutation.
// Grid-wide intra-kernel sync stays banned (rounds 9/12: 40-80us loss
// across 8 non-coherent XCD L2s).

#define H     16
#define OUTD  64
#define MM    8192                 // context/target count, fixed by harness
#define TILES 128
#define TROWS 64                   // rows per scan tile (MM/TILES)
#define RPT   4                    // rows per thread in scan (16 rg * 4 = 64)

// sortable mapping: monotone bijection float -> u32 (IEEE total order), then
// (s << 13) | idx gives a strict total order on (key, index).
__device__ __forceinline__ unsigned long long packkey(float f, int idx) {
    unsigned b = __float_as_uint(f);
    unsigned s = (b >> 31) ? ~b : (b | 0x80000000u);
    return ((unsigned long long)s << 13) | (unsigned)idx;
}
__device__ __forceinline__ float unpackkey(unsigned long long p) {
    unsigned s = (unsigned)(p >> 13);
    unsigned b = (s >> 31) ? (s ^ 0x80000000u) : ~s;
    return __uint_as_float(b);
}

// ---------------------------------------------------------------- K1
// 256 blocks x 1024. Block b: rank+scatter rows [32b,32b+32), MLP same rows.
__global__ __launch_bounds__(1024) void rank_mlp_kernel(
    const float* __restrict__ xc, const float* __restrict__ yc,
    const float* __restrict__ W1, const float* __restrict__ b1,
    const float* __restrict__ W2, const float* __restrict__ b2,
    const float* __restrict__ W3, const float* __restrict__ b3,
    float* __restrict__ vS, float* __restrict__ skey)
{
    __shared__ __align__(16) unsigned long long sk64[MM];  // packed keys, 64KB
    __shared__ int   red[32][4];      // [row][key-quarter] partial ranks
    __shared__ float sh2[32][H + 1];  // h2 per row, padded (17: coprime to 32)
    __shared__ int   rrk[32];         // rank of each of this block's 32 rows
    const int t = threadIdx.x;
    const int b = blockIdx.x;
    const int lane = t & 63, wid = t >> 6;

    // staging: thread t packs keys {g, g+1}, g = rr*2048 + 2t. float2 global
    // loads (8B coalesced); ulonglong2 LDS store at byte 16*(rr*1024+t):
    // lane-contiguous 16B -> conflict-free ds_write_b128.
#pragma unroll
    for (int rr = 0; rr < 4; rr++) {
        const int g = rr * 2048 + 2 * t;
        const float2 k2 = ((const float2*)xc)[rr * 1024 + t];
        ulonglong2 p;
        p.x = packkey(k2.x, g);
        p.y = packkey(k2.y, g + 1);
        ((ulonglong2*)sk64)[rr * 1024 + t] = p;
    }
    __syncthreads();

    // rank: wave wid -> row-group rg = wid>>2 (8 rows), key-quarter qt = wid&3.
    // Lane reads one lane-contiguous ulonglong2 per iter (ds_read_b128,
    // conflict-free). Count via ballot+popcount: v_cmp_lt_u64 on the VALU,
    // s_bcnt1_b64 + s_add on the SALU (concurrent pipes); cnt is wave-uniform
    // (SGPR), so no cross-lane reduction is needed afterwards.
    {
        const int rg = wid >> 2, qt = wid & 3;
        const int m0 = b * 32 + rg * 8;
        unsigned long long mp[8];
#pragma unroll
        for (int j = 0; j < 8; j++) mp[j] = sk64[m0 + j];  // wave-uniform
        int cnt[8] = {0, 0, 0, 0, 0, 0, 0, 0};
#pragma unroll
        for (int it = 0; it < 16; it++) {
            const ulonglong2 p =
                ((const ulonglong2*)sk64)[qt * 1024 + it * 64 + lane];
#pragma unroll
            for (int j = 0; j < 8; j++) {
                cnt[j] += __builtin_popcountll(__ballot(p.x < mp[j]));
                cnt[j] += __builtin_popcountll(__ballot(p.y < mp[j]));
            }
        }
        if (lane == 0) {
#pragma unroll
            for (int j = 0; j < 8; j++) red[rg * 8 + j][qt] = cnt[j];
        }
    }

    // MLP stage 1: h2 once per row (t<32). x recovered exactly from sk64.
    if (t < 32) {
        const int m = b * 32 + t;
        const float x = unpackkey(sk64[m]), y = yc[m];
        float h1[H];
#pragma unroll
        for (int j = 0; j < H; j++) {
            float a = x * W1[j] + y * W1[H + j] + b1[j];
            h1[j] = a > 0.f ? a : 0.f;
        }
#pragma unroll
        for (int j = 0; j < H; j++) {
            float a = b2[j];
#pragma unroll
            for (int i = 0; i < H; i++) a += h1[i] * W2[i * H + j];
            sh2[t][j] = a > 0.f ? a : 0.f;
        }
    }
    __syncthreads();

    // scatter (t<32): rank = sum of 4 partials, write sorted key + publish rank
    if (t < 32) {
        const int m = b * 32 + t;
        const int r = red[t][0] + red[t][1] + red[t][2] + red[t][3];
        skey[r] = unpackkey(sk64[m]);
        rrk[t] = r;
    }
    __syncthreads();   // stage 2 needs rrk

    // MLP stage 2: chp = t&31 lane-fast -> each half-wave writes one 256B
    // contiguous row vS[r][0..63] (float2 per lane). No false sharing: rows
    // are 256B-aligned and rank is a permutation (single writer per row).
    {
        const int chp = t & 31, ml = t >> 5;
        const int r = rrk[ml];
        const int cb = chp * 2;
        float a0 = b3[cb], a1 = b3[cb + 1];
#pragma unroll
        for (int i = 0; i < H; i++) {
            const float h = sh2[ml][i];          // half-wave-uniform broadcast
            const float2 w2 = ((const float2*)(W3 + i * OUTD))[chp];
            a0 += h * w2.x;
            a1 += h * w2.y;
        }
        ((float2*)(vS + (size_t)r * OUTD))[chp] = make_float2(a0, a1);
    }
}

// ---------------------------------------------------------------- K2a (scan)
// 128 blocks x 1024. Block = one 64-row tile x ALL 64 channels.
// Thread (c = t&63, rg = t>>6) accumulates 4 rows serially; block-level LDS
// scan over the 16 row-groups; writes WITHIN-TILE exclusive prefix LoT[j][c]
// and suffix HiT[j][c] as coalesced 256B rows, plus per-tile totals.
__global__ __launch_bounds__(1024) void scan_kernel(
    const float* __restrict__ skey, const float* __restrict__ vS,
    float* __restrict__ LoT, float* __restrict__ HiT,
    float* __restrict__ tileLo, float* __restrict__ tileHi)
{
    __shared__ float ldsLo[16][OUTD];
    __shared__ float ldsHi[16][OUTD];
    const int t = threadIdx.x;
    const int c = t & 63, rg = t >> 6;
    const int tile = blockIdx.x;
    const int i0 = tile * TROWS + rg * RPT;

    float wLo[RPT], wHi[RPT];
    float sLo = 0.f, sHi = 0.f;
#pragma unroll
    for (int r = 0; r < RPT; r++) {
        const int i = i0 + r;
        const float k = skey[i];                 // wave-uniform broadcast load
        const float v = vS[(size_t)i * OUTD + c]; // coalesced 256B row
        const float eP = __expf(k), eN = __expf(-k);
        wLo[r] = eP * v;
        wHi[r] = eN * v;
        sLo += wLo[r];
        sHi += wHi[r];
    }
    ldsLo[rg][c] = sLo;
    ldsHi[rg][c] = sHi;
    __syncthreads();

    float preLo = 0.f, sufHi = 0.f;              // tile-local scan offsets
#pragma unroll
    for (int g = 0; g < 16; g++) {
        const float a = ldsLo[g][c];
        const float bb = ldsHi[g][c];
        preLo += (g < rg) ? a : 0.f;
        sufHi += (g > rg) ? bb : 0.f;
    }

    float run = preLo;                           // exclusive prefix (Lo)
#pragma unroll
    for (int r = 0; r < RPT; r++) {
        LoT[(size_t)(i0 + r) * OUTD + c] = run;  // coalesced 256B row
        run += wLo[r];
    }
    float run2 = sufHi;                          // inclusive suffix (Hi)
#pragma unroll
    for (int r = RPT - 1; r >= 0; r--) {
        run2 += wHi[r];
        HiT[(size_t)(i0 + r) * OUTD + c] = run2; // coalesced 256B row
    }

    if (rg == 15) tileLo[tile * OUTD + c] = preLo + sLo;  // tile total
    if (rg == 0)  tileHi[tile * OUTD + c] = sufHi + sHi;  // tile total
}

// ---------------------------------------------------------------- K2b (query)
// 256 blocks x 1024. Block b answers targets [32b, 32b+32), one wave per 2
// targets (interleaved searches), lane = channel. Cross-tile prefixes built
// by ALL 1024 threads (16 groups x 8 tiles, two-pass group scan). All global
// reads/writes are coalesced 256B rows. No LDS padding needed: search reads
// are wave-uniform broadcasts.
__global__ __launch_bounds__(1024) void query_kernel(
    const float* __restrict__ xt, const float* __restrict__ skey,
    const float* __restrict__ LoT, const float* __restrict__ HiT,
    const float* __restrict__ tileLo, const float* __restrict__ tileHi,
    float* __restrict__ out)
{
    __shared__ float sk[MM];                     // sorted keys, 32KB
    __shared__ float tpLo [TILES + 1][OUTD];     // sum_{t'<t}  tileLo, 33KB
    __shared__ float tpHiA[TILES + 1][OUTD];     // sum_{t'>=t} tileHi, 33KB
    __shared__ float gLo[16][OUTD];              // group sums, 4KB
    __shared__ float gHi[16][OUTD];              // group sums, 4KB
    const int t = threadIdx.x;
    const int lane = t & 63, wid = t >> 6;
    const int bid = blockIdx.x;

    for (int i = t; i < MM / 4; i += 1024)       // float4 stage, conflict-free
        ((float4*)sk)[i] = ((const float4*)skey)[i];

    // tile-prefix build, all threads: (c = t&63, g = t>>6), group g owns
    // tiles [8g, 8g+8). Pass 1: group totals. Pass 2: cross-group offset
    // (16 LDS reads) + local running prefix -> tpLo/tpHiA rows.
    {
        const int c = t & 63, g = t >> 6;
        float tl[8], th[8];
        float sL = 0.f, sH = 0.f;
#pragma unroll
        for (int k = 0; k < 8; k++) {            // coalesced 256B rows
            tl[k] = tileLo[(8 * g + k) * OUTD + c];
            th[k] = tileHi[(8 * g + k) * OUTD + c];
            sL += tl[k];
            sH += th[k];
        }
        gLo[g][c] = sL;
        gHi[g][c] = sH;
        __syncthreads();

        float preL = 0.f, sufH = 0.f;
#pragma unroll
        for (int gg = 0; gg < 16; gg++) {
            const float a = gLo[gg][c];
            const float bb = gHi[gg][c];
            preL += (gg < g) ? a : 0.f;
            sufH += (gg > g) ? bb : 0.f;
        }
        float run = preL;                        // exclusive prefix of tiles
#pragma unroll
        for (int k = 0; k < 8; k++) {
            tpLo[8 * g + k][c] = run;
            run += tl[k];
        }
        float run2 = sufH;                       // suffix incl. own tiles
#pragma unroll
        for (int k = 7; k >= 0; k--) {
            run2 += th[k];
            tpHiA[8 * g + k][c] = run2;
        }
        if (g == 15) {                           // boundaries (lo == MM)
            tpLo[TILES][c] = run;                // total Lo sum
            tpHiA[TILES][c] = 0.f;               // nothing above top tile
        }
    }
    __syncthreads();

    // two interleaved wave-uniform 13-step lower_bounds (broadcast LDS reads)
    const int n0 = bid * 32 + wid * 2;
    const int n1 = n0 + 1;
    const float q0 = xt[n0], q1 = xt[n1];        // wave-uniform broadcasts
    int lo0 = 0, hi0v = MM, lo1 = 0, hi1v = MM;
#pragma unroll
    for (int s = 0; s < 13; s++) {               // 8192 = 2^13: exactly 13
        const int mid0 = (lo0 + hi0v) >> 1;
        const int mid1 = (lo1 + hi1v) >> 1;
        if (sk[mid0] < q0) lo0 = mid0 + 1; else hi0v = mid0;
        if (sk[mid1] < q1) lo1 = mid1 + 1; else hi1v = mid1;
    }

    // combine: Lo = tiles-before prefix + within-tile exclusive prefix;
    //          Hi = tiles-after suffix (tpHiA[t0+1]) + within-tile suffix.
    const int t0 = lo0 >> 6, t1 = lo1 >> 6;      // tile index (lo==MM -> 128)
    float L0 = tpLo[t0][lane], Hh0;
    float L1 = tpLo[t1][lane], Hh1;
    if (lo0 < MM) {                              // wave-uniform branch
        L0  += LoT[(size_t)lo0 * OUTD + lane];
        Hh0  = tpHiA[t0 + 1][lane] + HiT[(size_t)lo0 * OUTD + lane];
    } else {
        Hh0 = 0.f;                               // lo0 == MM: nothing above
    }
    if (lo1 < MM) {
        L1  += LoT[(size_t)lo1 * OUTD + lane];
        Hh1  = tpHiA[t1 + 1][lane] + HiT[(size_t)lo1 * OUTD + lane];
    } else {
        Hh1 = 0.f;
    }
    out[(size_t)n0 * OUTD + lane] = __expf(-q0) * L0 + __expf(q0) * Hh0;
    out[(size_t)n1 * OUTD + lane] = __expf(-q1) * L1 + __expf(q1) * Hh1;
}

extern "C" void kernel_launch(void* const* d_in, const int* in_sizes, int n_in,
                              void* d_out, int out_size, void* d_ws, size_t ws_size,
                              hipStream_t stream)
{
    const float* xc = (const float*)d_in[0];
    const float* yc = (const float*)d_in[1];
    const float* xt = (const float*)d_in[2];
    const float* W1 = (const float*)d_in[3];
    const float* b1 = (const float*)d_in[4];
    const float* W2 = (const float*)d_in[5];
    const float* b2 = (const float*)d_in[6];
    const float* W3 = (const float*)d_in[7];
    const float* b3 = (const float*)d_in[8];
    float* out = (float*)d_out;

    // workspace: vS [MM][64] (2MB) | skey [MM] (32KB) | LoT [MM][64] (2MB)
    //          | HiT [MM][64] (2MB) | tileLo [128][64] | tileHi [128][64]
    char* ws = (char*)d_ws;
    float* vS     = (float*)ws;
    float* skey   = (float*)(ws + (size_t)MM * OUTD * 4);
    float* LoT    = (float*)(ws + (size_t)MM * OUTD * 4 + (size_t)MM * 4);
    float* HiT    = LoT + (size_t)MM * OUTD;
    float* tileLo = HiT + (size_t)MM * OUTD;
    float* tileHi = tileLo + TILES * OUTD;

    rank_mlp_kernel<<<256, 1024, 0, stream>>>(xc, yc, W1, b1, W2, b2, W3, b3,
                                              vS, skey);
    scan_kernel<<<TILES, 1024, 0, stream>>>(skey, vS, LoT, HiT, tileLo, tileHi);
    query_kernel<<<256, 1024, 0, stream>>>(xt, skey, LoT, HiT, tileLo, tileHi,
                                           out);
}

// Round 9
// 88.965 us; speedup vs baseline: 1.0656x; 1.0656x over previous
//
#include <hip/hip_runtime.h>

// DeterministicEncoder: MLP encoder [M,2]->[M,64] + Laplace-kernel attention.
// exp(-|k-q|) factorizes: with context sorted by key, exclusive-prefix
// Lo[j] = sum_{i<j} e^{s_i} v_i and suffix Hi[j] = sum_{i>=j} e^{-s_i} v_i give
// out[n] = e^{-q} Lo[j_n] + e^{q} Hi[j_n], j_n = lower_bound(skey, q).
//
// Round 17: REVERT to round-15 (89.5us, session best). Round-16's
// ballot+popcount rank regressed to 94.8us: 256 v_cmp->SGPR handoffs + 512
// dependent SALU ops serialize (VALU->SALU hazard stalls, 1 op/cy SALU) and
// break the compiler's ds_read/compute pipelining -- worse than the simple
// per-lane v_cmp+v_addc it replaced. Ballot-reduce only pays as a FINAL
// reduction step, not inside a dense inner loop.
//
// Structure (all measured-verified):
//  - 3 plain stream-ordered kernels. Grid-wide intra-kernel sync is banned:
//    rounds 9/12 measured 40-80us loss (cooperative launch / fence+spin
//    across 8 non-coherent XCD L2s). Kernel boundary costs ~2us.
//  - All global arrays written as one 256B row per wave (lane = channel):
//    round 9 measured 8x write amplification for 4B column-strided stores.
//  - K1: u64-packed rank (1 cmp + 1 addc per element), lane-contiguous
//    ulonglong2 LDS accesses (conflict-free), 64KB LDS -> 2 blk/CU.
//  - K2a: 128 blocks (64-row tile x 64 channels each).
//  - K2b: tile prefixes built by all 1024 threads (two-pass group scan),
//    wave-uniform binary searches (broadcast LDS reads, no padding needed),
//    coalesced 256B row gathers + out stores.
// Ledger: ~80.8us of the 89.5 metric = two 256MiB harness poison fills at
// 82-84% HBM peak (their roofline, not ours); our slice ~8.7us vs ~6.5-7us
// launch-overhead floor.

#define H     16
#define OUTD  64
#define MM    8192                 // context/target count, fixed by harness
#define TILES 128
#define TROWS 64                   // rows per scan tile (MM/TILES)
#define RPT   4                    // rows per thread in scan (16 rg * 4 = 64)

// sortable mapping: monotone bijection float -> u32 (IEEE total order), then
// (s << 13) | idx gives a strict total order on (key, index).
__device__ __forceinline__ unsigned long long packkey(float f, int idx) {
    unsigned b = __float_as_uint(f);
    unsigned s = (b >> 31) ? ~b : (b | 0x80000000u);
    return ((unsigned long long)s << 13) | (unsigned)idx;
}
__device__ __forceinline__ float unpackkey(unsigned long long p) {
    unsigned s = (unsigned)(p >> 13);
    unsigned b = (s >> 31) ? (s ^ 0x80000000u) : ~s;
    return __uint_as_float(b);
}

// ---------------------------------------------------------------- K1
// 256 blocks x 1024. Block b: rank+scatter rows [32b,32b+32), MLP same rows.
__global__ __launch_bounds__(1024) void rank_mlp_kernel(
    const float* __restrict__ xc, const float* __restrict__ yc,
    const float* __restrict__ W1, const float* __restrict__ b1,
    const float* __restrict__ W2, const float* __restrict__ b2,
    const float* __restrict__ W3, const float* __restrict__ b3,
    float* __restrict__ vS, float* __restrict__ skey)
{
    __shared__ __align__(16) unsigned long long sk64[MM];  // packed keys, 64KB
    __shared__ int   red[32][4];      // [row][key-quarter] partial ranks
    __shared__ float sh2[32][H + 1];  // h2 per row, padded (17: coprime to 32)
    __shared__ int   rrk[32];         // rank of each of this block's 32 rows
    const int t = threadIdx.x;
    const int b = blockIdx.x;
    const int lane = t & 63, wid = t >> 6;

    // staging: thread t packs keys {g, g+1}, g = rr*2048 + 2t. float2 global
    // loads (8B coalesced); ulonglong2 LDS store at byte 16*(rr*1024+t):
    // lane-contiguous 16B -> conflict-free ds_write_b128.
#pragma unroll
    for (int rr = 0; rr < 4; rr++) {
        const int g = rr * 2048 + 2 * t;
        const float2 k2 = ((const float2*)xc)[rr * 1024 + t];
        ulonglong2 p;
        p.x = packkey(k2.x, g);
        p.y = packkey(k2.y, g + 1);
        ((ulonglong2*)sk64)[rr * 1024 + t] = p;
    }
    __syncthreads();

    // rank: wave wid -> row-group rg = wid>>2 (8 rows), key-quarter qt = wid&3.
    // Lane reads one lane-contiguous ulonglong2 per iter (ds_read_b128,
    // conflict-free); 2 keys x 8 rows x (v_cmp_lt_u64 + addc).
    {
        const int rg = wid >> 2, qt = wid & 3;
        const int m0 = b * 32 + rg * 8;
        unsigned long long mp[8];
#pragma unroll
        for (int j = 0; j < 8; j++) mp[j] = sk64[m0 + j];  // wave-uniform
        int cnt[8] = {0, 0, 0, 0, 0, 0, 0, 0};
#pragma unroll
        for (int it = 0; it < 16; it++) {
            const ulonglong2 p =
                ((const ulonglong2*)sk64)[qt * 1024 + it * 64 + lane];
#pragma unroll
            for (int j = 0; j < 8; j++) {
                cnt[j] += (p.x < mp[j]) ? 1 : 0;
                cnt[j] += (p.y < mp[j]) ? 1 : 0;
            }
        }
#pragma unroll
        for (int j = 0; j < 8; j++) {            // in-wave reduction
            int v = cnt[j];
#pragma unroll
            for (int off = 32; off; off >>= 1) v += __shfl_down(v, off);
            if (lane == 0) red[rg * 8 + j][qt] = v;
        }
    }

    // MLP stage 1: h2 once per row (t<32). x recovered exactly from sk64.
    if (t < 32) {
        const int m = b * 32 + t;
        const float x = unpackkey(sk64[m]), y = yc[m];
        float h1[H];
#pragma unroll
        for (int j = 0; j < H; j++) {
            float a = x * W1[j] + y * W1[H + j] + b1[j];
            h1[j] = a > 0.f ? a : 0.f;
        }
#pragma unroll
        for (int j = 0; j < H; j++) {
            float a = b2[j];
#pragma unroll
            for (int i = 0; i < H; i++) a += h1[i] * W2[i * H + j];
            sh2[t][j] = a > 0.f ? a : 0.f;
        }
    }
    __syncthreads();

    // scatter (t<32): rank = sum of 4 partials, write sorted key + publish rank
    if (t < 32) {
        const int m = b * 32 + t;
        const int r = red[t][0] + red[t][1] + red[t][2] + red[t][3];
        skey[r] = unpackkey(sk64[m]);
        rrk[t] = r;
    }
    __syncthreads();   // stage 2 needs rrk

    // MLP stage 2: chp = t&31 lane-fast -> each half-wave writes one 256B
    // contiguous row vS[r][0..63] (float2 per lane). No false sharing: rows
    // are 256B-aligned and rank is a permutation (single writer per row).
    {
        const int chp = t & 31, ml = t >> 5;
        const int r = rrk[ml];
        const int cb = chp * 2;
        float a0 = b3[cb], a1 = b3[cb + 1];
#pragma unroll
        for (int i = 0; i < H; i++) {
            const float h = sh2[ml][i];          // half-wave-uniform broadcast
            const float2 w2 = ((const float2*)(W3 + i * OUTD))[chp];
            a0 += h * w2.x;
            a1 += h * w2.y;
        }
        ((float2*)(vS + (size_t)r * OUTD))[chp] = make_float2(a0, a1);
    }
}

// ---------------------------------------------------------------- K2a (scan)
// 128 blocks x 1024. Block = one 64-row tile x ALL 64 channels.
// Thread (c = t&63, rg = t>>6) accumulates 4 rows serially; block-level LDS
// scan over the 16 row-groups; writes WITHIN-TILE exclusive prefix LoT[j][c]
// and suffix HiT[j][c] as coalesced 256B rows, plus per-tile totals.
__global__ __launch_bounds__(1024) void scan_kernel(
    const float* __restrict__ skey, const float* __restrict__ vS,
    float* __restrict__ LoT, float* __restrict__ HiT,
    float* __restrict__ tileLo, float* __restrict__ tileHi)
{
    __shared__ float ldsLo[16][OUTD];
    __shared__ float ldsHi[16][OUTD];
    const int t = threadIdx.x;
    const int c = t & 63, rg = t >> 6;
    const int tile = blockIdx.x;
    const int i0 = tile * TROWS + rg * RPT;

    float wLo[RPT], wHi[RPT];
    float sLo = 0.f, sHi = 0.f;
#pragma unroll
    for (int r = 0; r < RPT; r++) {
        const int i = i0 + r;
        const float k = skey[i];                 // wave-uniform broadcast load
        const float v = vS[(size_t)i * OUTD + c]; // coalesced 256B row
        const float eP = __expf(k), eN = __expf(-k);
        wLo[r] = eP * v;
        wHi[r] = eN * v;
        sLo += wLo[r];
        sHi += wHi[r];
    }
    ldsLo[rg][c] = sLo;
    ldsHi[rg][c] = sHi;
    __syncthreads();

    float preLo = 0.f, sufHi = 0.f;              // tile-local scan offsets
#pragma unroll
    for (int g = 0; g < 16; g++) {
        const float a = ldsLo[g][c];
        const float bb = ldsHi[g][c];
        preLo += (g < rg) ? a : 0.f;
        sufHi += (g > rg) ? bb : 0.f;
    }

    float run = preLo;                           // exclusive prefix (Lo)
#pragma unroll
    for (int r = 0; r < RPT; r++) {
        LoT[(size_t)(i0 + r) * OUTD + c] = run;  // coalesced 256B row
        run += wLo[r];
    }
    float run2 = sufHi;                          // inclusive suffix (Hi)
#pragma unroll
    for (int r = RPT - 1; r >= 0; r--) {
        run2 += wHi[r];
        HiT[(size_t)(i0 + r) * OUTD + c] = run2; // coalesced 256B row
    }

    if (rg == 15) tileLo[tile * OUTD + c] = preLo + sLo;  // tile total
    if (rg == 0)  tileHi[tile * OUTD + c] = sufHi + sHi;  // tile total
}

// ---------------------------------------------------------------- K2b (query)
// 256 blocks x 1024. Block b answers targets [32b, 32b+32), one wave per 2
// targets (interleaved searches), lane = channel. Cross-tile prefixes built
// by ALL 1024 threads (16 groups x 8 tiles, two-pass group scan). All global
// reads/writes are coalesced 256B rows. No LDS padding needed: search reads
// are wave-uniform broadcasts.
__global__ __launch_bounds__(1024) void query_kernel(
    const float* __restrict__ xt, const float* __restrict__ skey,
    const float* __restrict__ LoT, const float* __restrict__ HiT,
    const float* __restrict__ tileLo, const float* __restrict__ tileHi,
    float* __restrict__ out)
{
    __shared__ float sk[MM];                     // sorted keys, 32KB
    __shared__ float tpLo [TILES + 1][OUTD];     // sum_{t'<t}  tileLo, 33KB
    __shared__ float tpHiA[TILES + 1][OUTD];     // sum_{t'>=t} tileHi, 33KB
    __shared__ float gLo[16][OUTD];              // group sums, 4KB
    __shared__ float gHi[16][OUTD];              // group sums, 4KB
    const int t = threadIdx.x;
    const int lane = t & 63, wid = t >> 6;
    const int bid = blockIdx.x;

    for (int i = t; i < MM / 4; i += 1024)       // float4 stage, conflict-free
        ((float4*)sk)[i] = ((const float4*)skey)[i];

    // tile-prefix build, all threads: (c = t&63, g = t>>6), group g owns
    // tiles [8g, 8g+8). Pass 1: group totals. Pass 2: cross-group offset
    // (16 LDS reads) + local running prefix -> tpLo/tpHiA rows.
    {
        const int c = t & 63, g = t >> 6;
        float tl[8], th[8];
        float sL = 0.f, sH = 0.f;
#pragma unroll
        for (int k = 0; k < 8; k++) {            // coalesced 256B rows
            tl[k] = tileLo[(8 * g + k) * OUTD + c];
            th[k] = tileHi[(8 * g + k) * OUTD + c];
            sL += tl[k];
            sH += th[k];
        }
        gLo[g][c] = sL;
        gHi[g][c] = sH;
        __syncthreads();

        float preL = 0.f, sufH = 0.f;
#pragma unroll
        for (int gg = 0; gg < 16; gg++) {
            const float a = gLo[gg][c];
            const float bb = gHi[gg][c];
            preL += (gg < g) ? a : 0.f;
            sufH += (gg > g) ? bb : 0.f;
        }
        float run = preL;                        // exclusive prefix of tiles
#pragma unroll
        for (int k = 0; k < 8; k++) {
            tpLo[8 * g + k][c] = run;
            run += tl[k];
        }
        float run2 = sufH;                       // suffix incl. own tiles
#pragma unroll
        for (int k = 7; k >= 0; k--) {
            run2 += th[k];
            tpHiA[8 * g + k][c] = run2;
        }
        if (g == 15) {                           // boundaries (lo == MM)
            tpLo[TILES][c] = run;                // total Lo sum
            tpHiA[TILES][c] = 0.f;               // nothing above top tile
        }
    }
    __syncthreads();

    // two interleaved wave-uniform 13-step lower_bounds (broadcast LDS reads)
    const int n0 = bid * 32 + wid * 2;
    const int n1 = n0 + 1;
    const float q0 = xt[n0], q1 = xt[n1];        // wave-uniform broadcasts
    int lo0 = 0, hi0v = MM, lo1 = 0, hi1v = MM;
#pragma unroll
    for (int s = 0; s < 13; s++) {               // 8192 = 2^13: exactly 13
        const int mid0 = (lo0 + hi0v) >> 1;
        const int mid1 = (lo1 + hi1v) >> 1;
        if (sk[mid0] < q0) lo0 = mid0 + 1; else hi0v = mid0;
        if (sk[mid1] < q1) lo1 = mid1 + 1; else hi1v = mid1;
    }

    // combine: Lo = tiles-before prefix + within-tile exclusive prefix;
    //          Hi = tiles-after suffix (tpHiA[t0+1]) + within-tile suffix.
    const int t0 = lo0 >> 6, t1 = lo1 >> 6;      // tile index (lo==MM -> 128)
    float L0 = tpLo[t0][lane], Hh0;
    float L1 = tpLo[t1][lane], Hh1;
    if (lo0 < MM) {                              // wave-uniform branch
        L0  += LoT[(size_t)lo0 * OUTD + lane];
        Hh0  = tpHiA[t0 + 1][lane] + HiT[(size_t)lo0 * OUTD + lane];
    } else {
        Hh0 = 0.f;                               // lo0 == MM: nothing above
    }
    if (lo1 < MM) {
        L1  += LoT[(size_t)lo1 * OUTD + lane];
        Hh1  = tpHiA[t1 + 1][lane] + HiT[(size_t)lo1 * OUTD + lane];
    } else {
        Hh1 = 0.f;
    }
    out[(size_t)n0 * OUTD + lane] = __expf(-q0) * L0 + __expf(q0) * Hh0;
    out[(size_t)n1 * OUTD + lane] = __expf(-q1) * L1 + __expf(q1) * Hh1;
}

extern "C" void kernel_launch(void* const* d_in, const int* in_sizes, int n_in,
                              void* d_out, int out_size, void* d_ws, size_t ws_size,
                              hipStream_t stream)
{
    const float* xc = (const float*)d_in[0];
    const float* yc = (const float*)d_in[1];
    const float* xt = (const float*)d_in[2];
    const float* W1 = (const float*)d_in[3];
    const float* b1 = (const float*)d_in[4];
    const float* W2 = (const float*)d_in[5];
    const float* b2 = (const float*)d_in[6];
    const float* W3 = (const float*)d_in[7];
    const float* b3 = (const float*)d_in[8];
    float* out = (float*)d_out;

    // workspace: vS [MM][64] (2MB) | skey [MM] (32KB) | LoT [MM][64] (2MB)
    //          | HiT [MM][64] (2MB) | tileLo [128][64] | tileHi [128][64]
    char* ws = (char*)d_ws;
    float* vS     = (float*)ws;
    float* skey   = (float*)(ws + (size_t)MM * OUTD * 4);
    float* LoT    = (float*)(ws + (size_t)MM * OUTD * 4 + (size_t)MM * 4);
    float* HiT    = LoT + (size_t)MM * OUTD;
    float* tileLo = HiT + (size_t)MM * OUTD;
    float* tileHi = tileLo + TILES * OUTD;

    rank_mlp_kernel<<<256, 1024, 0, stream>>>(xc, yc, W1, b1, W2, b2, W3, b3,
                                              vS, skey);
    scan_kernel<<<TILES, 1024, 0, stream>>>(skey, vS, LoT, HiT, tileLo, tileHi);
    query_kernel<<<256, 1024, 0, stream>>>(xt, skey, LoT, HiT, tileLo, tileHi,
                                           out);
}